// Round 4
// baseline (584.190 us; speedup 1.0000x reference)
//
#include <hip/hip_runtime.h>

// B=4, S=2048, D=512, H=8, DK=DV=64
typedef __attribute__((ext_vector_type(8))) short short8;
typedef __attribute__((ext_vector_type(4))) float f32x4;

__device__ __forceinline__ short f2bf(float f) {
  union { float f; unsigned u; } x; x.f = f;
  return (short)((x.u + 0x7FFFu + ((x.u >> 16) & 1u)) >> 16);
}
__device__ __forceinline__ unsigned pk2(float a, float b) {
  return (unsigned)(unsigned short)f2bf(a) | ((unsigned)(unsigned short)f2bf(b) << 16);
}

// Wt[m][n][k] = W_m[k][n], bf16  (3 x 512 x 512)
__global__ __launch_bounds__(256) void prep_wt_k(const float* __restrict__ Wq,
    const float* __restrict__ Wk, const float* __restrict__ Wv,
    short* __restrict__ wt) {
  int idx = blockIdx.x * 256 + threadIdx.x;
  int m = idx >> 18;
  int r = idx & 0x3FFFF;
  int k = r >> 9, n = r & 511;
  const float* W = (m == 0) ? Wq : (m == 1) ? Wk : Wv;
  wt[(m << 18) + (n << 9) + k] = f2bf(W[(k << 9) + n]);
}

// convert q,k,v f32 -> bf16 [3][8192][512]
__global__ __launch_bounds__(256) void xcvt_k(const float* __restrict__ q,
    const float* __restrict__ k_, const float* __restrict__ v,
    short* __restrict__ xb) {
  int i = blockIdx.x * 256 + threadIdx.x;
  int m = i >> 19;
  int r = i & 0x7FFFF;
  const float* X = (m == 0) ? q : (m == 1) ? k_ : v;
  float4 f0 = ((const float4*)X)[2 * r];
  float4 f1 = ((const float4*)X)[2 * r + 1];
  short8 t;
  t[0] = f2bf(f0.x); t[1] = f2bf(f0.y); t[2] = f2bf(f0.z); t[3] = f2bf(f0.w);
  t[4] = f2bf(f1.x); t[5] = f2bf(f1.y); t[6] = f2bf(f1.z); t[7] = f2bf(f1.w);
  *(short8*)(xb + (size_t)i * 8) = t;
}

// X[8192][512] @ Wt[n][k] -> qh [b][h][s][64], kh row-permuted, vt [b][h][dv][s]
template<int BF>
__global__ __launch_bounds__(64) void proj_k(const float* __restrict__ q,
    const float* __restrict__ k_, const float* __restrict__ v,
    const short* __restrict__ xb, const short* __restrict__ wt,
    short* __restrict__ qh, short* __restrict__ kh, short* __restrict__ vt) {
  int bid = blockIdx.x;
  int mat = bid >> 10;
  int t = bid & 1023;
  int tm = t >> 3, tn = t & 7;
  const float* X = (mat == 0) ? q : (mat == 1) ? k_ : v;
  const short* Xb = xb + ((size_t)mat << 22);
  const short* W = wt + ((size_t)mat << 18);
  int lane = threadIdx.x;
  int lr = lane & 15, lg = lane >> 4;
  int m0 = tm << 6, n0 = tn << 6;
  f32x4 acc[4][4];
  #pragma unroll
  for (int i = 0; i < 4; i++)
    #pragma unroll
    for (int j = 0; j < 4; j++) acc[i][j] = (f32x4){0.f, 0.f, 0.f, 0.f};
  for (int k0 = 0; k0 < 512; k0 += 32) {
    short8 a[4], bfr[4];
    #pragma unroll
    for (int i = 0; i < 4; i++) {
      if (BF) {
        a[i] = *(const short8*)(Xb + (size_t)(m0 + 16 * i + lr) * 512 + k0 + 8 * lg);
      } else {
        const float* p = X + (size_t)(m0 + 16 * i + lr) * 512 + k0 + 8 * lg;
        float4 f0 = *(const float4*)p;
        float4 f1 = *(const float4*)(p + 4);
        short8 tt;
        tt[0] = f2bf(f0.x); tt[1] = f2bf(f0.y); tt[2] = f2bf(f0.z); tt[3] = f2bf(f0.w);
        tt[4] = f2bf(f1.x); tt[5] = f2bf(f1.y); tt[6] = f2bf(f1.z); tt[7] = f2bf(f1.w);
        a[i] = tt;
      }
    }
    #pragma unroll
    for (int j = 0; j < 4; j++)
      bfr[j] = *(const short8*)(W + (size_t)(n0 + 16 * j + lr) * 512 + k0 + 8 * lg);
    #pragma unroll
    for (int i = 0; i < 4; i++)
      #pragma unroll
      for (int j = 0; j < 4; j++)
        acc[i][j] = __builtin_amdgcn_mfma_f32_16x16x32_bf16(a[i], bfr[j], acc[i][j], 0, 0, 0);
  }
  #pragma unroll
  for (int i = 0; i < 4; i++)
    #pragma unroll
    for (int j = 0; j < 4; j++)
      #pragma unroll
      for (int r = 0; r < 4; r++) {
        int row = m0 + 16 * i + lg * 4 + r;
        int col = n0 + 16 * j + lr;
        int bb = row >> 11, s = row & 2047;
        int h = col >> 6, d = col & 63;
        short val = f2bf(acc[i][j][r]);
        if (mat == 0) {
          qh[((size_t)((bb * 8 + h) * 2048 + s) << 6) + d] = val;
        } else if (mat == 1) {
          // permuted row slot so attn's QK^T output is PV-A-fragment-aligned:
          // within each 32-row block: orig o=8a+b -> slot (b<4 ? 4a+b : 16+4a+b-4)
          int o = s & 31, aa = o >> 3, b7 = o & 7;
          int loc = (b7 < 4) ? ((aa << 2) | b7) : (16 + ((aa << 2) | (b7 - 4)));
          int sp = (s & ~31) | loc;
          kh[((size_t)((bb * 8 + h) * 2048 + sp) << 6) + d] = val;
        } else {
          vt[((size_t)((bb * 8 + h) * 64 + d) << 11) + s] = val;
        }
      }
}

__device__ __forceinline__ float eterm(float s, float m, float cs, float gl2, float sh2) {
  return __builtin_amdgcn_exp2f(fmaf(s, cs, fmaf(m, gl2, -sh2)));
}

// swapped-operand attention, permuted-K storage: no cross-lane ops at all.
// Lane (lr,lg): q-row = qb+lr, owns k-cols kc+8lg..kc+8lg+7 (contiguous).
__global__ __launch_bounds__(128) void attn_k(const short* __restrict__ qh,
    const short* __restrict__ kh, const short* __restrict__ vt,
    const float* __restrict__ mask, const float* __restrict__ gamma_p,
    float* __restrict__ out, float* __restrict__ attn_out) {
  int bid = blockIdx.x;
  int bh = bid >> 6;
  int qblk = bid & 63;
  int bb = bh >> 3, h = bh & 7;
  int wave = threadIdx.x >> 6;
  int lane = threadIdx.x & 63;
  int lr = lane & 15, lg = lane >> 4;
  int qb = (qblk << 5) + (wave << 4);
  int qg = qb + lr;
  const short* Kb = kh + (size_t)bh * (2048 * 64);
  const short* Qb = qh + (size_t)bh * (2048 * 64);
  const short* Vb = vt + (size_t)bh * (64 * 2048);
  const float* Mp = mask + (size_t)bb * (2048 * 2048) + (size_t)qg * 2048 + (lg << 3);
  float* Ap = attn_out + ((size_t)bh * 2048 + qg) * 2048 + (lg << 3);
  const float LOG2E = 1.4426950408889634f;
  float gamma = gamma_p[0];
  float shift = fmaxf(gamma, 0.f) + 16.0f;
  float cs = 0.125f * LOG2E;
  float gl2 = gamma * LOG2E;
  float sh2 = shift * LOG2E;

  short8 qf0 = *(const short8*)(Qb + (size_t)qg * 64 + 8 * lg);
  short8 qf1 = *(const short8*)(Qb + (size_t)qg * 64 + 32 + 8 * lg);

  // ---- pass A: row sums, mask prefetched one 64-col iteration ahead ----
  float lsum = 0.f;
  float4 ca0 = *(const float4*)(Mp + 0);
  float4 ca1 = *(const float4*)(Mp + 4);
  float4 cb0 = *(const float4*)(Mp + 32);
  float4 cb1 = *(const float4*)(Mp + 36);
  for (int kc = 0; kc < 2048; kc += 64) {
    int kn = (kc + 64) & 2047;
    float4 na0 = *(const float4*)(Mp + kn);
    float4 na1 = *(const float4*)(Mp + kn + 4);
    float4 nb0 = *(const float4*)(Mp + kn + 32);
    float4 nb1 = *(const float4*)(Mp + kn + 36);
    const short* kp = Kb + (size_t)(kc + lr) * 64 + (lg << 3);
    short8 kf00 = *(const short8*)(kp);
    short8 kf01 = *(const short8*)(kp + 32);
    short8 kf10 = *(const short8*)(kp + 16 * 64);
    short8 kf11 = *(const short8*)(kp + 16 * 64 + 32);
    short8 kg00 = *(const short8*)(kp + 32 * 64);
    short8 kg01 = *(const short8*)(kp + 32 * 64 + 32);
    short8 kg10 = *(const short8*)(kp + 48 * 64);
    short8 kg11 = *(const short8*)(kp + 48 * 64 + 32);
    f32x4 s0 = (f32x4){0.f, 0.f, 0.f, 0.f};
    s0 = __builtin_amdgcn_mfma_f32_16x16x32_bf16(kf00, qf0, s0, 0, 0, 0);
    s0 = __builtin_amdgcn_mfma_f32_16x16x32_bf16(kf01, qf1, s0, 0, 0, 0);
    f32x4 s1 = (f32x4){0.f, 0.f, 0.f, 0.f};
    s1 = __builtin_amdgcn_mfma_f32_16x16x32_bf16(kf10, qf0, s1, 0, 0, 0);
    s1 = __builtin_amdgcn_mfma_f32_16x16x32_bf16(kf11, qf1, s1, 0, 0, 0);
    f32x4 t0 = (f32x4){0.f, 0.f, 0.f, 0.f};
    t0 = __builtin_amdgcn_mfma_f32_16x16x32_bf16(kg00, qf0, t0, 0, 0, 0);
    t0 = __builtin_amdgcn_mfma_f32_16x16x32_bf16(kg01, qf1, t0, 0, 0, 0);
    f32x4 t1 = (f32x4){0.f, 0.f, 0.f, 0.f};
    t1 = __builtin_amdgcn_mfma_f32_16x16x32_bf16(kg10, qf0, t1, 0, 0, 0);
    t1 = __builtin_amdgcn_mfma_f32_16x16x32_bf16(kg11, qf1, t1, 0, 0, 0);
    lsum += eterm(s0[0], ca0.x, cs, gl2, sh2);
    lsum += eterm(s0[1], ca0.y, cs, gl2, sh2);
    lsum += eterm(s0[2], ca0.z, cs, gl2, sh2);
    lsum += eterm(s0[3], ca0.w, cs, gl2, sh2);
    lsum += eterm(s1[0], ca1.x, cs, gl2, sh2);
    lsum += eterm(s1[1], ca1.y, cs, gl2, sh2);
    lsum += eterm(s1[2], ca1.z, cs, gl2, sh2);
    lsum += eterm(s1[3], ca1.w, cs, gl2, sh2);
    lsum += eterm(t0[0], cb0.x, cs, gl2, sh2);
    lsum += eterm(t0[1], cb0.y, cs, gl2, sh2);
    lsum += eterm(t0[2], cb0.z, cs, gl2, sh2);
    lsum += eterm(t0[3], cb0.w, cs, gl2, sh2);
    lsum += eterm(t1[0], cb1.x, cs, gl2, sh2);
    lsum += eterm(t1[1], cb1.y, cs, gl2, sh2);
    lsum += eterm(t1[2], cb1.z, cs, gl2, sh2);
    lsum += eterm(t1[3], cb1.w, cs, gl2, sh2);
    ca0 = na0; ca1 = na1; cb0 = nb0; cb1 = nb1;
  }
  lsum += __shfl_xor(lsum, 16);
  lsum += __shfl_xor(lsum, 32);
  float inv = 1.0f / lsum;

  // ---- pass B ----
  f32x4 oacc[4];
  #pragma unroll
  for (int j = 0; j < 4; j++) oacc[j] = (f32x4){0.f, 0.f, 0.f, 0.f};

  ca0 = *(const float4*)(Mp + 0);
  ca1 = *(const float4*)(Mp + 4);
  cb0 = *(const float4*)(Mp + 32);
  cb1 = *(const float4*)(Mp + 36);
  for (int kc = 0; kc < 2048; kc += 64) {
    int kn = (kc + 64) & 2047;
    float4 na0 = *(const float4*)(Mp + kn);
    float4 na1 = *(const float4*)(Mp + kn + 4);
    float4 nb0 = *(const float4*)(Mp + kn + 32);
    float4 nb1 = *(const float4*)(Mp + kn + 36);
    const short* kp = Kb + (size_t)(kc + lr) * 64 + (lg << 3);
    short8 kf00 = *(const short8*)(kp);
    short8 kf01 = *(const short8*)(kp + 32);
    short8 kf10 = *(const short8*)(kp + 16 * 64);
    short8 kf11 = *(const short8*)(kp + 16 * 64 + 32);
    short8 kg00 = *(const short8*)(kp + 32 * 64);
    short8 kg01 = *(const short8*)(kp + 32 * 64 + 32);
    short8 kg10 = *(const short8*)(kp + 48 * 64);
    short8 kg11 = *(const short8*)(kp + 48 * 64 + 32);

    // half 0 (cols kc .. kc+31)
    const short* vp0 = Vb + (size_t)lr * 2048 + kc + (lg << 3);
    short8 vf0 = *(const short8*)(vp0);
    short8 vf1 = *(const short8*)(vp0 + 16 * 2048);
    short8 vf2 = *(const short8*)(vp0 + 32 * 2048);
    short8 vf3 = *(const short8*)(vp0 + 48 * 2048);
    f32x4 s0 = (f32x4){0.f, 0.f, 0.f, 0.f};
    s0 = __builtin_amdgcn_mfma_f32_16x16x32_bf16(kf00, qf0, s0, 0, 0, 0);
    s0 = __builtin_amdgcn_mfma_f32_16x16x32_bf16(kf01, qf1, s0, 0, 0, 0);
    f32x4 s1 = (f32x4){0.f, 0.f, 0.f, 0.f};
    s1 = __builtin_amdgcn_mfma_f32_16x16x32_bf16(kf10, qf0, s1, 0, 0, 0);
    s1 = __builtin_amdgcn_mfma_f32_16x16x32_bf16(kf11, qf1, s1, 0, 0, 0);
    float p00 = eterm(s0[0], ca0.x, cs, gl2, sh2) * inv;
    float p01 = eterm(s0[1], ca0.y, cs, gl2, sh2) * inv;
    float p02 = eterm(s0[2], ca0.z, cs, gl2, sh2) * inv;
    float p03 = eterm(s0[3], ca0.w, cs, gl2, sh2) * inv;
    float p10 = eterm(s1[0], ca1.x, cs, gl2, sh2) * inv;
    float p11 = eterm(s1[1], ca1.y, cs, gl2, sh2) * inv;
    float p12 = eterm(s1[2], ca1.z, cs, gl2, sh2) * inv;
    float p13 = eterm(s1[3], ca1.w, cs, gl2, sh2) * inv;
    float4 w0; w0.x = p00; w0.y = p01; w0.z = p02; w0.w = p03;
    float4 w1; w1.x = p10; w1.y = p11; w1.z = p12; w1.w = p13;
    *(float4*)(Ap + kc) = w0;
    *(float4*)(Ap + kc + 4) = w1;
    union { unsigned u[4]; short8 s8; } pu;
    pu.u[0] = pk2(p00, p01);
    pu.u[1] = pk2(p02, p03);
    pu.u[2] = pk2(p10, p11);
    pu.u[3] = pk2(p12, p13);
    oacc[0] = __builtin_amdgcn_mfma_f32_16x16x32_bf16(pu.s8, vf0, oacc[0], 0, 0, 0);
    oacc[1] = __builtin_amdgcn_mfma_f32_16x16x32_bf16(pu.s8, vf1, oacc[1], 0, 0, 0);
    oacc[2] = __builtin_amdgcn_mfma_f32_16x16x32_bf16(pu.s8, vf2, oacc[2], 0, 0, 0);
    oacc[3] = __builtin_amdgcn_mfma_f32_16x16x32_bf16(pu.s8, vf3, oacc[3], 0, 0, 0);

    // half 1 (cols kc+32 .. kc+63)
    const short* vp1 = vp0 + 32;
    short8 ve0 = *(const short8*)(vp1);
    short8 ve1 = *(const short8*)(vp1 + 16 * 2048);
    short8 ve2 = *(const short8*)(vp1 + 32 * 2048);
    short8 ve3 = *(const short8*)(vp1 + 48 * 2048);
    f32x4 t0 = (f32x4){0.f, 0.f, 0.f, 0.f};
    t0 = __builtin_amdgcn_mfma_f32_16x16x32_bf16(kg00, qf0, t0, 0, 0, 0);
    t0 = __builtin_amdgcn_mfma_f32_16x16x32_bf16(kg01, qf1, t0, 0, 0, 0);
    f32x4 t1 = (f32x4){0.f, 0.f, 0.f, 0.f};
    t1 = __builtin_amdgcn_mfma_f32_16x16x32_bf16(kg10, qf0, t1, 0, 0, 0);
    t1 = __builtin_amdgcn_mfma_f32_16x16x32_bf16(kg11, qf1, t1, 0, 0, 0);
    float q00 = eterm(t0[0], cb0.x, cs, gl2, sh2) * inv;
    float q01 = eterm(t0[1], cb0.y, cs, gl2, sh2) * inv;
    float q02 = eterm(t0[2], cb0.z, cs, gl2, sh2) * inv;
    float q03 = eterm(t0[3], cb0.w, cs, gl2, sh2) * inv;
    float q10 = eterm(t1[0], cb1.x, cs, gl2, sh2) * inv;
    float q11 = eterm(t1[1], cb1.y, cs, gl2, sh2) * inv;
    float q12 = eterm(t1[2], cb1.z, cs, gl2, sh2) * inv;
    float q13 = eterm(t1[3], cb1.w, cs, gl2, sh2) * inv;
    float4 w2; w2.x = q00; w2.y = q01; w2.z = q02; w2.w = q03;
    float4 w3; w3.x = q10; w3.y = q11; w3.z = q12; w3.w = q13;
    *(float4*)(Ap + kc + 32) = w2;
    *(float4*)(Ap + kc + 36) = w3;
    union { unsigned u[4]; short8 s8; } qu;
    qu.u[0] = pk2(q00, q01);
    qu.u[1] = pk2(q02, q03);
    qu.u[2] = pk2(q10, q11);
    qu.u[3] = pk2(q12, q13);
    oacc[0] = __builtin_amdgcn_mfma_f32_16x16x32_bf16(qu.s8, ve0, oacc[0], 0, 0, 0);
    oacc[1] = __builtin_amdgcn_mfma_f32_16x16x32_bf16(qu.s8, ve1, oacc[1], 0, 0, 0);
    oacc[2] = __builtin_amdgcn_mfma_f32_16x16x32_bf16(qu.s8, ve2, oacc[2], 0, 0, 0);
    oacc[3] = __builtin_amdgcn_mfma_f32_16x16x32_bf16(qu.s8, ve3, oacc[3], 0, 0, 0);

    ca0 = na0; ca1 = na1; cb0 = nb0; cb1 = nb1;
  }

  #pragma unroll
  for (int j = 0; j < 4; j++)
    #pragma unroll
    for (int r = 0; r < 4; r++) {
      int qq = qb + (lg << 2) + r;
      out[((size_t)(bb * 2048) + qq) * 512 + (h << 6) + (j << 4) + lr] = oacc[j][r];
    }
}

extern "C" void kernel_launch(void* const* d_in, const int* in_sizes, int n_in,
                              void* d_out, int out_size, void* d_ws, size_t ws_size,
                              hipStream_t stream) {
  const float* q    = (const float*)d_in[0];
  const float* k    = (const float*)d_in[1];
  const float* v    = (const float*)d_in[2];
  const float* mask = (const float*)d_in[3];
  const float* Wq   = (const float*)d_in[4];
  const float* Wk   = (const float*)d_in[5];
  const float* Wv   = (const float*)d_in[6];
  const float* gma  = (const float*)d_in[7];
  float* out = (float*)d_out;
  float* attn_out = out + (size_t)4 * 2048 * 512;

  short* wt = (short*)d_ws;                              // 1.5 MB
  short* qh = (short*)((char*)d_ws + (2u << 20));        // 8 MB
  short* kh = qh + (size_t)4 * 8 * 2048 * 64;            // 8 MB (row-permuted)
  short* vt = kh + (size_t)4 * 8 * 2048 * 64;            // 8 MB
  short* xb = vt + (size_t)4 * 8 * 2048 * 64;            // 24 MB (optional)
  bool big_ws = ws_size >= (size_t)(50u << 20);

  hipLaunchKernelGGL(prep_wt_k, dim3(3072), dim3(256), 0, stream, Wq, Wk, Wv, wt);
  if (big_ws) {
    hipLaunchKernelGGL(xcvt_k, dim3(6144), dim3(256), 0, stream, q, k, v, xb);
    hipLaunchKernelGGL(proj_k<1>, dim3(3072), dim3(64), 0, stream, q, k, v, xb, wt, qh, kh, vt);
  } else {
    hipLaunchKernelGGL(proj_k<0>, dim3(3072), dim3(64), 0, stream, q, k, v, xb, wt, qh, kh, vt);
  }
  hipLaunchKernelGGL(attn_k, dim3(2048), dim3(128), 0, stream, qh, kh, vt, mask, gma,
                     out, attn_out);
}

// Round 5
// 542.208 us; speedup vs baseline: 1.0774x; 1.0774x over previous
//
#include <hip/hip_runtime.h>

// B=4, S=2048, D=512, H=8, DK=DV=64
typedef __attribute__((ext_vector_type(8))) short short8;
typedef __attribute__((ext_vector_type(4))) float f32x4;

__device__ __forceinline__ short f2bf(float f) {
  union { float f; unsigned u; } x; x.f = f;
  return (short)((x.u + 0x7FFFu + ((x.u >> 16) & 1u)) >> 16);
}
__device__ __forceinline__ unsigned pk2(float a, float b) {
  return (unsigned)(unsigned short)f2bf(a) | ((unsigned)(unsigned short)f2bf(b) << 16);
}
__device__ __forceinline__ float bfu2f(unsigned lo16) {
  union { unsigned u; float f; } x; x.u = lo16 << 16; return x.f;
}

// Wt[m][n][k] = W_m[k][n], bf16  (3 x 512 x 512)
__global__ __launch_bounds__(256) void prep_wt_k(const float* __restrict__ Wq,
    const float* __restrict__ Wk, const float* __restrict__ Wv,
    short* __restrict__ wt) {
  int idx = blockIdx.x * 256 + threadIdx.x;
  int m = idx >> 18;
  int r = idx & 0x3FFFF;
  int k = r >> 9, n = r & 511;
  const float* W = (m == 0) ? Wq : (m == 1) ? Wk : Wv;
  wt[(m << 18) + (n << 9) + k] = f2bf(W[(k << 9) + n]);
}

// convert q,k,v f32 -> bf16 [3][8192][512]
__global__ __launch_bounds__(256) void xcvt_k(const float* __restrict__ q,
    const float* __restrict__ k_, const float* __restrict__ v,
    short* __restrict__ xb) {
  int i = blockIdx.x * 256 + threadIdx.x;
  int m = i >> 19;
  int r = i & 0x7FFFF;
  const float* X = (m == 0) ? q : (m == 1) ? k_ : v;
  float4 f0 = ((const float4*)X)[2 * r];
  float4 f1 = ((const float4*)X)[2 * r + 1];
  short8 t;
  t[0] = f2bf(f0.x); t[1] = f2bf(f0.y); t[2] = f2bf(f0.z); t[3] = f2bf(f0.w);
  t[4] = f2bf(f1.x); t[5] = f2bf(f1.y); t[6] = f2bf(f1.z); t[7] = f2bf(f1.w);
  *(short8*)(xb + (size_t)i * 8) = t;
}

// X[8192][512] @ Wt[n][k] -> qh [b][h][s][64], kh row-permuted, vt [b][h][dv][s]
template<int BF>
__global__ __launch_bounds__(64) void proj_k(const float* __restrict__ q,
    const float* __restrict__ k_, const float* __restrict__ v,
    const short* __restrict__ xb, const short* __restrict__ wt,
    short* __restrict__ qh, short* __restrict__ kh, short* __restrict__ vt) {
  int bid = blockIdx.x;
  int mat = bid >> 10;
  int t = bid & 1023;
  int tm = t >> 3, tn = t & 7;
  const float* X = (mat == 0) ? q : (mat == 1) ? k_ : v;
  const short* Xb = xb + ((size_t)mat << 22);
  const short* W = wt + ((size_t)mat << 18);
  int lane = threadIdx.x;
  int lr = lane & 15, lg = lane >> 4;
  int m0 = tm << 6, n0 = tn << 6;
  f32x4 acc[4][4];
  #pragma unroll
  for (int i = 0; i < 4; i++)
    #pragma unroll
    for (int j = 0; j < 4; j++) acc[i][j] = (f32x4){0.f, 0.f, 0.f, 0.f};
  for (int k0 = 0; k0 < 512; k0 += 32) {
    short8 a[4], bfr[4];
    #pragma unroll
    for (int i = 0; i < 4; i++) {
      if (BF) {
        a[i] = *(const short8*)(Xb + (size_t)(m0 + 16 * i + lr) * 512 + k0 + 8 * lg);
      } else {
        const float* p = X + (size_t)(m0 + 16 * i + lr) * 512 + k0 + 8 * lg;
        float4 f0 = *(const float4*)p;
        float4 f1 = *(const float4*)(p + 4);
        short8 tt;
        tt[0] = f2bf(f0.x); tt[1] = f2bf(f0.y); tt[2] = f2bf(f0.z); tt[3] = f2bf(f0.w);
        tt[4] = f2bf(f1.x); tt[5] = f2bf(f1.y); tt[6] = f2bf(f1.z); tt[7] = f2bf(f1.w);
        a[i] = tt;
      }
    }
    #pragma unroll
    for (int j = 0; j < 4; j++)
      bfr[j] = *(const short8*)(W + (size_t)(n0 + 16 * j + lr) * 512 + k0 + 8 * lg);
    #pragma unroll
    for (int i = 0; i < 4; i++)
      #pragma unroll
      for (int j = 0; j < 4; j++)
        acc[i][j] = __builtin_amdgcn_mfma_f32_16x16x32_bf16(a[i], bfr[j], acc[i][j], 0, 0, 0);
  }
  #pragma unroll
  for (int i = 0; i < 4; i++)
    #pragma unroll
    for (int j = 0; j < 4; j++)
      #pragma unroll
      for (int r = 0; r < 4; r++) {
        int row = m0 + 16 * i + lg * 4 + r;
        int col = n0 + 16 * j + lr;
        int bb = row >> 11, s = row & 2047;
        int h = col >> 6, d = col & 63;
        short val = f2bf(acc[i][j][r]);
        if (mat == 0) {
          qh[((size_t)((bb * 8 + h) * 2048 + s) << 6) + d] = val;
        } else if (mat == 1) {
          int o = s & 31, aa = o >> 3, b7 = o & 7;
          int loc = (b7 < 4) ? ((aa << 2) | b7) : (16 + ((aa << 2) | (b7 - 4)));
          int sp = (s & ~31) | loc;
          kh[((size_t)((bb * 8 + h) * 2048 + sp) << 6) + d] = val;
        } else {
          vt[((size_t)((bb * 8 + h) * 64 + d) << 11) + s] = val;
        }
      }
}

__device__ __forceinline__ float eterm(float s, float m, float cs, float gl2, float sh2) {
  return __builtin_amdgcn_exp2f(fmaf(s, cs, fmaf(m, gl2, -sh2)));
}

// Block = (batch, 16 q-rows) x all 8 heads. Wave w = head w.
// Mask tile staged ONCE in LDS, shared by 8 heads. attn written in 1KB bursts.
__global__ __launch_bounds__(512) void attn_k(const short* __restrict__ qh,
    const short* __restrict__ kh, const short* __restrict__ vt,
    const float* __restrict__ mask, const float* __restrict__ gamma_p,
    float* __restrict__ out, float* __restrict__ attn_out) {
  __shared__ __align__(16) short P_lds[8][16][256];   // 64 KB (per-wave P tiles)
  __shared__ __align__(16) float M_lds[16][256];      // 16 KB (shared mask tile)

  int bid = blockIdx.x;
  int bb = bid >> 7;
  int q0 = (bid & 127) << 4;
  int w = threadIdx.x >> 6;                 // head
  int lane = threadIdx.x & 63;
  int lr = lane & 15, lg = lane >> 4;
  int bh = bb * 8 + w;
  const short* Kb = kh + (size_t)bh * (2048 * 64);
  const short* Qb = qh + (size_t)bh * (2048 * 64);
  const short* Vb = vt + (size_t)bh * (64 * 2048);
  const float* Mb = mask + (size_t)bb * (2048 * 2048);
  float* Ab = attn_out + (size_t)bh * (2048 * 2048);
  const float LOG2E = 1.4426950408889634f;
  float gamma = gamma_p[0];
  float shift = fmaxf(gamma, 0.f) + 16.0f;
  float cs = 0.125f * LOG2E;
  float gl2 = gamma * LOG2E;
  float sh2 = shift * LOG2E;

  // mask staging assignment: thread t stages 8 floats of row (t>>5), unit (t&31)
  int srow = threadIdx.x >> 5;
  int sc8 = threadIdx.x & 31;
  const float* msrc = Mb + (size_t)(q0 + srow) * 2048 + (sc8 << 3);
  float* mdst = &M_lds[srow][((sc8 ^ (srow & 7)) << 3)];

  short8 qf0 = *(const short8*)(Qb + (size_t)(q0 + lr) * 64 + 8 * lg);
  short8 qf1 = *(const short8*)(Qb + (size_t)(q0 + lr) * 64 + 32 + 8 * lg);
  const float* mrd = &M_lds[lr][0];
  int sw = lr & 7;                            // mask/P swizzle key for this lane

  // ================= pass A: row sums =================
  float lsum = 0.f;
  for (int kc = 0; kc < 2048; kc += 256) {
    float4 mg0 = *(const float4*)(msrc + kc);
    float4 mg1 = *(const float4*)(msrc + kc + 4);
    *(float4*)mdst = mg0;
    *(float4*)(mdst + 4) = mg1;
    __syncthreads();
    #pragma unroll
    for (int sub = 0; sub < 4; ++sub) {
      int c0 = sub << 6;
      const short* kp = Kb + (size_t)(kc + c0 + lr) * 64 + (lg << 3);
      short8 kf00 = *(const short8*)(kp);
      short8 kf01 = *(const short8*)(kp + 32);
      short8 kf10 = *(const short8*)(kp + 16 * 64);
      short8 kf11 = *(const short8*)(kp + 16 * 64 + 32);
      short8 kg00 = *(const short8*)(kp + 32 * 64);
      short8 kg01 = *(const short8*)(kp + 32 * 64 + 32);
      short8 kg10 = *(const short8*)(kp + 48 * 64);
      short8 kg11 = *(const short8*)(kp + 48 * 64 + 32);
      f32x4 s0 = (f32x4){0.f, 0.f, 0.f, 0.f};
      s0 = __builtin_amdgcn_mfma_f32_16x16x32_bf16(kf00, qf0, s0, 0, 0, 0);
      s0 = __builtin_amdgcn_mfma_f32_16x16x32_bf16(kf01, qf1, s0, 0, 0, 0);
      f32x4 s1 = (f32x4){0.f, 0.f, 0.f, 0.f};
      s1 = __builtin_amdgcn_mfma_f32_16x16x32_bf16(kf10, qf0, s1, 0, 0, 0);
      s1 = __builtin_amdgcn_mfma_f32_16x16x32_bf16(kf11, qf1, s1, 0, 0, 0);
      f32x4 t0 = (f32x4){0.f, 0.f, 0.f, 0.f};
      t0 = __builtin_amdgcn_mfma_f32_16x16x32_bf16(kg00, qf0, t0, 0, 0, 0);
      t0 = __builtin_amdgcn_mfma_f32_16x16x32_bf16(kg01, qf1, t0, 0, 0, 0);
      f32x4 t1 = (f32x4){0.f, 0.f, 0.f, 0.f};
      t1 = __builtin_amdgcn_mfma_f32_16x16x32_bf16(kg10, qf0, t1, 0, 0, 0);
      t1 = __builtin_amdgcn_mfma_f32_16x16x32_bf16(kg11, qf1, t1, 0, 0, 0);
      int u0 = (((c0 >> 3) + lg) ^ sw) << 3;
      int u1 = (((c0 >> 3) + 4 + lg) ^ sw) << 3;
      float4 ca0 = *(const float4*)(mrd + u0);
      float4 ca1 = *(const float4*)(mrd + u0 + 4);
      float4 cb0 = *(const float4*)(mrd + u1);
      float4 cb1 = *(const float4*)(mrd + u1 + 4);
      lsum += eterm(s0[0], ca0.x, cs, gl2, sh2);
      lsum += eterm(s0[1], ca0.y, cs, gl2, sh2);
      lsum += eterm(s0[2], ca0.z, cs, gl2, sh2);
      lsum += eterm(s0[3], ca0.w, cs, gl2, sh2);
      lsum += eterm(s1[0], ca1.x, cs, gl2, sh2);
      lsum += eterm(s1[1], ca1.y, cs, gl2, sh2);
      lsum += eterm(s1[2], ca1.z, cs, gl2, sh2);
      lsum += eterm(s1[3], ca1.w, cs, gl2, sh2);
      lsum += eterm(t0[0], cb0.x, cs, gl2, sh2);
      lsum += eterm(t0[1], cb0.y, cs, gl2, sh2);
      lsum += eterm(t0[2], cb0.z, cs, gl2, sh2);
      lsum += eterm(t0[3], cb0.w, cs, gl2, sh2);
      lsum += eterm(t1[0], cb1.x, cs, gl2, sh2);
      lsum += eterm(t1[1], cb1.y, cs, gl2, sh2);
      lsum += eterm(t1[2], cb1.z, cs, gl2, sh2);
      lsum += eterm(t1[3], cb1.w, cs, gl2, sh2);
    }
    __syncthreads();
  }
  lsum += __shfl_xor(lsum, 16);
  lsum += __shfl_xor(lsum, 32);
  float inv = 1.0f / lsum;

  // ================= pass B =================
  f32x4 oacc[4];
  #pragma unroll
  for (int j = 0; j < 4; j++) oacc[j] = (f32x4){0.f, 0.f, 0.f, 0.f};

  for (int kc = 0; kc < 2048; kc += 256) {
    float4 mg0 = *(const float4*)(msrc + kc);
    float4 mg1 = *(const float4*)(msrc + kc + 4);
    *(float4*)mdst = mg0;
    *(float4*)(mdst + 4) = mg1;
    __syncthreads();
    #pragma unroll
    for (int sub = 0; sub < 4; ++sub) {
      int c0 = sub << 6;
      const short* kp = Kb + (size_t)(kc + c0 + lr) * 64 + (lg << 3);
      short8 kf00 = *(const short8*)(kp);
      short8 kf01 = *(const short8*)(kp + 32);
      short8 kf10 = *(const short8*)(kp + 16 * 64);
      short8 kf11 = *(const short8*)(kp + 16 * 64 + 32);
      short8 kg00 = *(const short8*)(kp + 32 * 64);
      short8 kg01 = *(const short8*)(kp + 32 * 64 + 32);
      short8 kg10 = *(const short8*)(kp + 48 * 64);
      short8 kg11 = *(const short8*)(kp + 48 * 64 + 32);
      int u0 = (((c0 >> 3) + lg) ^ sw) << 3;
      int u1 = (((c0 >> 3) + 4 + lg) ^ sw) << 3;
      float4 ca0 = *(const float4*)(mrd + u0);
      float4 ca1 = *(const float4*)(mrd + u0 + 4);
      float4 cb0 = *(const float4*)(mrd + u1);
      float4 cb1 = *(const float4*)(mrd + u1 + 4);

      // half 0: cols c0 .. c0+31
      const short* vp0 = Vb + (size_t)lr * 2048 + kc + c0 + (lg << 3);
      short8 vf0 = *(const short8*)(vp0);
      short8 vf1 = *(const short8*)(vp0 + 16 * 2048);
      short8 vf2 = *(const short8*)(vp0 + 32 * 2048);
      short8 vf3 = *(const short8*)(vp0 + 48 * 2048);
      f32x4 s0 = (f32x4){0.f, 0.f, 0.f, 0.f};
      s0 = __builtin_amdgcn_mfma_f32_16x16x32_bf16(kf00, qf0, s0, 0, 0, 0);
      s0 = __builtin_amdgcn_mfma_f32_16x16x32_bf16(kf01, qf1, s0, 0, 0, 0);
      f32x4 s1 = (f32x4){0.f, 0.f, 0.f, 0.f};
      s1 = __builtin_amdgcn_mfma_f32_16x16x32_bf16(kf10, qf0, s1, 0, 0, 0);
      s1 = __builtin_amdgcn_mfma_f32_16x16x32_bf16(kf11, qf1, s1, 0, 0, 0);
      float p00 = eterm(s0[0], ca0.x, cs, gl2, sh2) * inv;
      float p01 = eterm(s0[1], ca0.y, cs, gl2, sh2) * inv;
      float p02 = eterm(s0[2], ca0.z, cs, gl2, sh2) * inv;
      float p03 = eterm(s0[3], ca0.w, cs, gl2, sh2) * inv;
      float p10 = eterm(s1[0], ca1.x, cs, gl2, sh2) * inv;
      float p11 = eterm(s1[1], ca1.y, cs, gl2, sh2) * inv;
      float p12 = eterm(s1[2], ca1.z, cs, gl2, sh2) * inv;
      float p13 = eterm(s1[3], ca1.w, cs, gl2, sh2) * inv;
      union { unsigned u[4]; short8 s8; uint4 q4; } pu;
      pu.u[0] = pk2(p00, p01);
      pu.u[1] = pk2(p02, p03);
      pu.u[2] = pk2(p10, p11);
      pu.u[3] = pk2(p12, p13);
      {
        int c16 = (c0 >> 3) + lg;           // 16B units within [0,32)
        *(uint4*)&P_lds[w][lr][(c16 ^ sw) << 3] = pu.q4;
      }
      oacc[0] = __builtin_amdgcn_mfma_f32_16x16x32_bf16(pu.s8, vf0, oacc[0], 0, 0, 0);
      oacc[1] = __builtin_amdgcn_mfma_f32_16x16x32_bf16(pu.s8, vf1, oacc[1], 0, 0, 0);
      oacc[2] = __builtin_amdgcn_mfma_f32_16x16x32_bf16(pu.s8, vf2, oacc[2], 0, 0, 0);
      oacc[3] = __builtin_amdgcn_mfma_f32_16x16x32_bf16(pu.s8, vf3, oacc[3], 0, 0, 0);

      // half 1: cols c0+32 .. c0+63
      const short* vp1 = vp0 + 32;
      short8 ve0 = *(const short8*)(vp1);
      short8 ve1 = *(const short8*)(vp1 + 16 * 2048);
      short8 ve2 = *(const short8*)(vp1 + 32 * 2048);
      short8 ve3 = *(const short8*)(vp1 + 48 * 2048);
      f32x4 t0 = (f32x4){0.f, 0.f, 0.f, 0.f};
      t0 = __builtin_amdgcn_mfma_f32_16x16x32_bf16(kg00, qf0, t0, 0, 0, 0);
      t0 = __builtin_amdgcn_mfma_f32_16x16x32_bf16(kg01, qf1, t0, 0, 0, 0);
      f32x4 t1 = (f32x4){0.f, 0.f, 0.f, 0.f};
      t1 = __builtin_amdgcn_mfma_f32_16x16x32_bf16(kg10, qf0, t1, 0, 0, 0);
      t1 = __builtin_amdgcn_mfma_f32_16x16x32_bf16(kg11, qf1, t1, 0, 0, 0);
      float q00 = eterm(t0[0], cb0.x, cs, gl2, sh2) * inv;
      float q01 = eterm(t0[1], cb0.y, cs, gl2, sh2) * inv;
      float q02 = eterm(t0[2], cb0.z, cs, gl2, sh2) * inv;
      float q03 = eterm(t0[3], cb0.w, cs, gl2, sh2) * inv;
      float q10 = eterm(t1[0], cb1.x, cs, gl2, sh2) * inv;
      float q11 = eterm(t1[1], cb1.y, cs, gl2, sh2) * inv;
      float q12 = eterm(t1[2], cb1.z, cs, gl2, sh2) * inv;
      float q13 = eterm(t1[3], cb1.w, cs, gl2, sh2) * inv;
      union { unsigned u[4]; short8 s8; uint4 q4; } qu;
      qu.u[0] = pk2(q00, q01);
      qu.u[1] = pk2(q02, q03);
      qu.u[2] = pk2(q10, q11);
      qu.u[3] = pk2(q12, q13);
      {
        int c16 = (c0 >> 3) + 4 + lg;
        *(uint4*)&P_lds[w][lr][(c16 ^ sw) << 3] = qu.q4;
      }
      oacc[0] = __builtin_amdgcn_mfma_f32_16x16x32_bf16(qu.s8, ve0, oacc[0], 0, 0, 0);
      oacc[1] = __builtin_amdgcn_mfma_f32_16x16x32_bf16(qu.s8, ve1, oacc[1], 0, 0, 0);
      oacc[2] = __builtin_amdgcn_mfma_f32_16x16x32_bf16(qu.s8, ve2, oacc[2], 0, 0, 0);
      oacc[3] = __builtin_amdgcn_mfma_f32_16x16x32_bf16(qu.s8, ve3, oacc[3], 0, 0, 0);
    }
    // flush this wave's 16x256 P tile as 1KB-contiguous row bursts
    asm volatile("s_waitcnt lgkmcnt(0)" ::: "memory");
    __builtin_amdgcn_sched_barrier(0);
    #pragma unroll
    for (int r = 0; r < 16; ++r) {
      const unsigned* pr = (const unsigned*)&P_lds[w][r]
          [(((lane >> 1) ^ (r & 7)) << 3) + ((lane & 1) << 2)];
      uint2 pv = *(const uint2*)pr;
      float4 o;
      o.x = bfu2f(pv.x & 0xFFFFu);
      o.y = bfu2f(pv.x >> 16);
      o.z = bfu2f(pv.y & 0xFFFFu);
      o.w = bfu2f(pv.y >> 16);
      *(float4*)(Ab + (size_t)(q0 + r) * 2048 + kc + (lane << 2)) = o;
    }
    __syncthreads();
  }

  int h = w;
  #pragma unroll
  for (int j = 0; j < 4; j++)
    #pragma unroll
    for (int r = 0; r < 4; r++) {
      int qq = q0 + (lg << 2) + r;
      out[((size_t)(bb * 2048) + qq) * 512 + (h << 6) + (j << 4) + lr] = oacc[j][r];
    }
}

extern "C" void kernel_launch(void* const* d_in, const int* in_sizes, int n_in,
                              void* d_out, int out_size, void* d_ws, size_t ws_size,
                              hipStream_t stream) {
  const float* q    = (const float*)d_in[0];
  const float* k    = (const float*)d_in[1];
  const float* v    = (const float*)d_in[2];
  const float* mask = (const float*)d_in[3];
  const float* Wq   = (const float*)d_in[4];
  const float* Wk   = (const float*)d_in[5];
  const float* Wv   = (const float*)d_in[6];
  const float* gma  = (const float*)d_in[7];
  float* out = (float*)d_out;
  float* attn_out = out + (size_t)4 * 2048 * 512;

  short* wt = (short*)d_ws;                              // 1.5 MB
  short* qh = (short*)((char*)d_ws + (2u << 20));        // 8 MB
  short* kh = qh + (size_t)4 * 8 * 2048 * 64;            // 8 MB (row-permuted)
  short* vt = kh + (size_t)4 * 8 * 2048 * 64;            // 8 MB
  short* xb = vt + (size_t)4 * 8 * 2048 * 64;            // 24 MB (optional)
  bool big_ws = ws_size >= (size_t)(50u << 20);

  hipLaunchKernelGGL(prep_wt_k, dim3(3072), dim3(256), 0, stream, Wq, Wk, Wv, wt);
  if (big_ws) {
    hipLaunchKernelGGL(xcvt_k, dim3(6144), dim3(256), 0, stream, q, k, v, xb);
    hipLaunchKernelGGL(proj_k<1>, dim3(3072), dim3(64), 0, stream, q, k, v, xb, wt, qh, kh, vt);
  } else {
    hipLaunchKernelGGL(proj_k<0>, dim3(3072), dim3(64), 0, stream, q, k, v, xb, wt, qh, kh, vt);
  }
  hipLaunchKernelGGL(attn_k, dim3(512), dim3(512), 0, stream, qh, kh, vt, mask, gma,
                     out, attn_out);
}